// Round 11
// baseline (160.531 us; speedup 1.0000x reference)
//
#include <hip/hip_runtime.h>

// Problem constants (match reference)
#define DHW   (128*128*128)        // 2^21
#define CDHW  (4*DHW)              // 2^23
#define NTOT  (2*CDHW)             // 2^24 = 16,777,216
#define NACC  1024                 // one accumulator slot per tile

// fused (erode2) tiling: full x-row (32 f4), 8 owned y-rows, 16 owned z.
#define ROW4     32
#define IN_ROWS  12                // 8 + 2*2 y-halo
#define S1_ROWS  10                // 8 + 2*1
#define IN_P4    (IN_ROWS*ROW4)    // 384 f4 / input plane
#define S1_P4    (S1_ROWS*ROW4)    // 320 f4 / s1 plane
#define SLOT4(z) (((z)+8)&3)       // 4-slot ring
#define SLOT2(z) (((z)+8)&1)       // 2-slot ring

// Flag word per tile: 16-bit mask, bit (z-zb) = plane z has a nonzero.
// tile id = (bc<<7) | (tz<<4) | ty.

// ---------------------------------------------------------------------------
// Fused pass 0 (R7/R10, proven, byte-identical): softmax + (p-onehot)^2
// during staging, then TWO erosion steps; per-plane vote-gated stores +
// 16-bit plane-mask flags. Initializes accs[blockIdx.x].
// ---------------------------------------------------------------------------
__global__ __launch_bounds__(256, 4) void fused_sm_erode2_kernel(
    const float* __restrict__ in, const int* __restrict__ tgt,
    float4* __restrict__ dst,
    const float* __restrict__ kern, const float* __restrict__ bias,
    const float* __restrict__ weight, float c1, float c2,
    double* __restrict__ accs, int* __restrict__ flagOut)
{
    __shared__ float4 lin[4 * IN_P4];
    __shared__ float4 ls1[2 * S1_P4];
    __shared__ double wsum[4];
    __shared__ int    voteArr[16];

    const int tid = threadIdx.x;
    const int x  = blockIdx.x & 7;
    const int q  = blockIdx.x >> 3;
    const int c  = q & 3;
    const int t  = x * 32 + (q >> 2);
    const int y0 = (t & 15) << 3;
    const int zb = ((t >> 4) & 7) << 4;
    const int b  = (t >> 7) & 1;
    const int bc = b * 4 + c;
    const int fid = (bc << 7) | (((t >> 4) & 7) << 4) | (t & 15);

    const float4* in4 = (const float4*)in;
    const int4*   tg4 = (const int4*)tgt;
    const size_t  chb = ((size_t)(b * 4)) << 19;
    const size_t  co0 = chb + ((size_t)c << 19);
    const size_t  co1 = chb + ((size_t)((c + 1) & 3) << 19);
    const size_t  co2 = chb + ((size_t)((c + 2) & 3) << 19);
    const size_t  co3 = chb + ((size_t)((c + 3) & 3) << 19);
    float4*       dp  = dst + ((size_t)bc << 19);
    const float wk = kern[13];
    const float bs = bias[c];

    const int col  = tid & 31;
    const int trow = tid >> 5;

    if (tid < 16) voteArr[tid] = 0;

    const int  gy0  = y0 + trow - 2;
    const bool lv0  = ((unsigned)gy0 < 128u);
    const int  off0 = (lv0 ? gy0 : 0) * 32 + col;
    const bool act1 = (tid < 128);
    const int  gy1  = y0 + trow + 6;
    const bool lv1  = act1 && ((unsigned)gy1 < 128u);
    const int  off1 = (lv1 ? gy1 : 0) * 32 + col;

    const bool  sact1 = (tid < 64);
    const int   sr  = (tid < 32) ? 0 : 9;
    const float m1  = ((unsigned)(y0 + sr - 1) < 128u) ? 1.f : 0.f;
    const int   ci1 = (sr + 1) * 32 + (tid & 31);
    const int   so1 = sr * 32 + (tid & 31);

    const float lmask = (col == 0)  ? 0.f : 1.f;
    const float rmask = (col == 31) ? 0.f : 1.f;

    const int go4 = (y0 + trow) * 32 + col;

    const float4 f4z = make_float4(0.f, 0.f, 0.f, 0.f);
    float4 A00 = f4z, A01 = f4z, A02 = f4z, A03 = f4z;
    float4 A10 = f4z, A11 = f4z, A12 = f4z, A13 = f4z;
    int4   T0 = make_int4(0,0,0,0), T1 = make_int4(0,0,0,0);
    bool   ok0 = false, ok1 = false;
    float4 s_m = f4z, s_c = f4z, s_p = f4z;
    float4 vH  = f4z;

    auto prefetch = [&](int L) {
        const bool zok = ((unsigned)L < 128u);
        ok0 = zok && lv0;
        ok1 = zok && lv1;
        if (ok0) {
            size_t o = (size_t)(L << 12) + off0;
            A00 = in4[co0 + o];
            A01 = in4[co1 + o];
            A02 = in4[co2 + o];
            A03 = in4[co3 + o];
            T0  = tg4[((size_t)b << 19) + o];
        }
        if (ok1) {
            size_t o = (size_t)(L << 12) + off1;
            A10 = in4[co0 + o];
            A11 = in4[co1 + o];
            A12 = in4[co2 + o];
            A13 = in4[co3 + o];
            T1  = tg4[((size_t)b << 19) + o];
        }
    };
    auto op_one = [&](const float4& B0, const float4& B1, const float4& B2,
                      const float4& B3, const int4& T) -> float4 {
        float4 r;
        #define OP1(K)                                                         \
        {                                                                      \
            float vc = B0.K;                                                   \
            float sm = 1.0f + __expf(B1.K - vc) + __expf(B2.K - vc)            \
                            + __expf(B3.K - vc);                               \
            float d  = __builtin_amdgcn_rcpf(sm) - ((T.K == c) ? 1.0f : 0.0f); \
            r.K = d * d;                                                       \
        }
        OP1(x) OP1(y) OP1(z) OP1(w)
        #undef OP1
        return r;
    };
    auto commit = [&](int L) {
        float4* sl = lin + SLOT4(L) * IN_P4;
        float4 v0 = f4z, v1 = f4z;
        if (ok0) v0 = op_one(A00, A01, A02, A03, T0);
        if (ok1) v1 = op_one(A10, A11, A12, A13, T1);
        sl[tid] = v0;
        if (act1) sl[256 + tid] = v1;
    };
    auto s1one = [&](const float4* pzm, const float4* pzc, const float4* pzp,
                     int ci, float ym) -> float4 {
        float4 qC = pzc[ci];
        float4 qU = pzc[ci - 32];
        float4 qD = pzc[ci + 32];
        float4 qm = pzm[ci];
        float4 qp = pzp[ci];
        float lf = __shfl_up(qC.w, 1, 64)   * lmask;
        float rt = __shfl_down(qC.x, 1, 64) * rmask;
        float4 v;
        v.x = fmaxf((qC.x + lf   + qC.y + qU.x + qD.x + qm.x + qp.x) * wk + bs, 0.f) * ym;
        v.y = fmaxf((qC.y + qC.x + qC.z + qU.y + qD.y + qm.y + qp.y) * wk + bs, 0.f) * ym;
        v.z = fmaxf((qC.z + qC.y + qC.w + qU.z + qD.z + qm.z + qp.z) * wk + bs, 0.f) * ym;
        v.w = fmaxf((qC.w + qC.z + rt   + qU.w + qD.w + qm.w + qp.w) * wk + bs, 0.f) * ym;
        return v;
    };
    auto s1_phase = [&](int z) {
        float4* o = ls1 + SLOT2(z) * S1_P4;
        float4 vnew;
        if ((unsigned)z < 128u) {
            const float4* pzm = lin + SLOT4(z - 1) * IN_P4;
            const float4* pzc = lin + SLOT4(z)     * IN_P4;
            const float4* pzp = lin + SLOT4(z + 1) * IN_P4;
            vnew = s1one(pzm, pzc, pzp, tid + 64, 1.f);
            o[tid + 32] = vnew;
            if (sact1) o[so1] = s1one(pzm, pzc, pzp, ci1, m1);
        } else {
            vnew = f4z;
            o[tid + 32] = f4z;
            if (sact1) o[so1] = f4z;
        }
        s_m = s_c; s_c = s_p; s_p = vnew;
    };

    double part = 0.0;

    prefetch(zb - 2); commit(zb - 2);
    prefetch(zb - 1); commit(zb - 1);
    prefetch(zb);     commit(zb);
    prefetch(zb + 1);
    __syncthreads();
    s1_phase(zb - 1);

    for (int L = zb + 1; L <= zb + 17; ++L) {
        commit(L);
        __syncthreads();                    // publishes votes for zp = L-3
        const int zp = L - 3;
        if (zp >= zb && voteArr[zp - zb] != 0)
            dp[((size_t)zp << 12) + go4] = vH;
        if (L <= zb + 16) prefetch(L + 1);
        s1_phase(L - 1);
        const int zo = L - 2;
        if (zo >= zb) {
            const float4* su = ls1 + SLOT2(zo) * S1_P4;
            float4 u4 = su[tid];
            float4 d4 = su[tid + 64];
            float lf = __shfl_up(s_c.w, 1, 64)   * lmask;
            float rt = __shfl_down(s_c.x, 1, 64) * rmask;
            float4 v;
            v.x = fmaxf((s_c.x + lf    + s_c.y + u4.x + d4.x + s_m.x + s_p.x) * wk + bs, 0.f);
            v.y = fmaxf((s_c.y + s_c.x + s_c.z + u4.y + d4.y + s_m.y + s_p.y) * wk + bs, 0.f);
            v.z = fmaxf((s_c.z + s_c.y + s_c.w + u4.z + d4.z + s_m.z + s_p.z) * wk + bs, 0.f);
            v.w = fmaxf((s_c.w + s_c.z + rt    + u4.w + d4.w + s_m.w + s_p.w) * wk + bs, 0.f);
            float pl = c1 * (s_c.x + s_c.y + s_c.z + s_c.w)
                     + c2 * (v.x   + v.y   + v.z   + v.w);
            part += (double)pl;
            bool nzv = (v.x != 0.f) || (v.y != 0.f) || (v.z != 0.f) || (v.w != 0.f);
            if (__any(nzv) && (tid & 63) == 0) atomicOr(&voteArr[zo - zb], 1);
            vH = v;
        }
    }

    __syncthreads();
    if (voteArr[15] != 0) dp[((size_t)(zb + 15) << 12) + go4] = vH;

    #pragma unroll
    for (int off = 32; off > 0; off >>= 1)
        part += __shfl_down(part, off, 64);
    if ((tid & 63) == 0) wsum[tid >> 6] = part;
    __syncthreads();
    if (tid == 0) {
        int mask = 0;
        #pragma unroll
        for (int i = 0; i < 16; ++i) mask |= (voteArr[i] ? 1 : 0) << i;
        flagOut[fid] = mask;
        double tot = (wsum[0] + wsum[1] + wsum[2] + wsum[3]) * (double)weight[bc];
        accs[blockIdx.x] = tot;
    }
}

// ---------------------------------------------------------------------------
// wl_build: one thread per tile. Evaluates EXACTLY erode4's aIn!=0 predicate
// (3x3 neighbor masks; dz=-1 contributes bits 12-15, dz=+1 bits 0-3) and
// compacts active tiles into wl[1..]; wl[0] = count. Also zeroes the pass's
// flagOut (active erode4 blocks overwrite) and the pop counter.
// ---------------------------------------------------------------------------
__global__ __launch_bounds__(1024) void wl_build_kernel(
    const int* __restrict__ flagIn, int* __restrict__ flagOut,
    int* __restrict__ wl, int* __restrict__ popc)
{
    const int t = threadIdx.x;            // tile id 0..1023
    flagOut[t] = 0;
    if (t == 0) { wl[0] = 0; popc[0] = 0; }
    __syncthreads();                      // wl[0]=0 visible before appends

    const int ty = t & 15, tz = (t >> 4) & 7, bc = t >> 7;
    int act = 0;
    #pragma unroll
    for (int dz = -1; dz <= 1; ++dz) {
        int zt = tz + dz;
        if ((unsigned)zt >= 8u) continue;
        int need = (dz < 0) ? 0xF000 : (dz > 0) ? 0x000F : 0xFFFF;
        #pragma unroll
        for (int dy = -1; dy <= 1; ++dy) {
            int yt = ty + dy;
            if ((unsigned)yt >= 16u) continue;
            act |= flagIn[(bc << 7) | (zt << 4) | yt] & need;
        }
    }
    if (act) { int i = atomicAdd(&wl[0], 1); wl[1 + i] = t; }
}

// ---------------------------------------------------------------------------
// erode4 (worklist-driven): FOUR fused erosion steps. Fixed 256-block grid;
// blocks pop tiles from the worklist (atomic counter). Per-tile body = R10's
// verified march (ballot activity, trimmed range, vote-gated stores).
// ---------------------------------------------------------------------------
#define E4_INP4  512   // 16 rows * 32
#define E4_S1P4  448   // 14 rows * 32
#define E4_S2P4  384   // 12 rows * 32
#define E4_S3P4  320   // 10 rows * 32

__global__ __launch_bounds__(256, 2) void erode4_kernel(
    const float4* __restrict__ src, float4* __restrict__ dst,
    const float* __restrict__ kern, const float* __restrict__ bias,
    const float* __restrict__ weight,
    float c1, float c2, float c3, float c4,
    int store, double* __restrict__ accs,
    const int* __restrict__ flagIn, int* __restrict__ flagOut,
    const int* __restrict__ wl, int* __restrict__ popc)
{
    __shared__ float4 lin[4 * E4_INP4];   // 32 KB
    __shared__ float4 ls1[2 * E4_S1P4];   // 14 KB
    __shared__ float4 ls2[2 * E4_S2P4];   // 12 KB
    __shared__ float4 ls3[2 * E4_S3P4];   // 10 KB
    __shared__ double wsum[4];
    __shared__ int    sf[9];
    __shared__ int    voteArr[16];
    __shared__ unsigned sAIn;
    __shared__ int    sTile;

    const int tid  = threadIdx.x;
    const int cnt  = wl[0];
    const int col  = tid & 31;
    const int trow = tid >> 5;
    const int g    = trow;
    const float wk = kern[13];
    const float lmask = (col == 0)  ? 0.f : 1.f;
    const float rmask = (col == 31) ? 0.f : 1.f;
    const float4 f4z = make_float4(0.f, 0.f, 0.f, 0.f);

    for (;;) {
        if (tid == 0) {
            int i = atomicAdd(popc, 1);
            sTile = (i < cnt) ? wl[1 + i] : -1;
        }
        __syncthreads();
        const int tile = sTile;
        __syncthreads();
        if (tile < 0) break;

        const int ty = tile & 15;
        const int tz = (tile >> 4) & 7;
        const int y0 = ty << 3;
        const int zb = tz << 4;
        const int bc = tile >> 7;

        if (tid < 9) {
            int dy = tid % 3 - 1, dz = tid / 3 - 1;
            int yt = ty + dy, zt = tz + dz;
            int f = 0;
            if ((unsigned)yt < 16u && (unsigned)zt < 8u)
                f = flagIn[(bc << 7) | (zt << 4) | yt];
            sf[tid] = f;
        }
        __syncthreads();

        bool abit = false;
        if (tid < 24) {
            int L = zb - 4 + tid;
            if ((unsigned)L < 128u) {
                int zi = (L >> 4) - tz + 1;
                int m  = sf[zi * 3] | sf[zi * 3 + 1] | sf[zi * 3 + 2];
                abit = (m >> (L & 15)) & 1;
            }
        }
        unsigned long long bal = __ballot(abit);
        if (tid == 0) sAIn = (unsigned)bal;
        __syncthreads();
        const unsigned aIn = sAIn;
        if (aIn == 0) continue;         // WL predicate == aIn!=0, but be safe

        unsigned zc = 0xFFFFFFu;
        if (zb == 0)   zc &= 0xFFFFF0u;
        if (zb == 112) zc &= 0x0FFFFFu;
        const unsigned a1 = (aIn | aIn << 1 | aIn >> 1) & zc & 0x7FFFFEu;
        const unsigned a2 = (a1  | a1  << 1 | a1  >> 1) & zc & 0x3FFFFCu;
        const unsigned a3 = (a2  | a2  << 1 | a2  >> 1) & zc & 0x1FFFF8u;
        const unsigned a4 = (a3  | a3  << 1 | a3  >> 1) & zc & 0x0FFFF0u;

        if (tid < 16) voteArr[tid] = 0; // published by first in-march barrier

        const int fa  = __builtin_ctz(aIn);
        const int la  = 31 - __builtin_clz(aIn);
        const int loL = zb - 4 + (fa > 2 ? fa - 2 : 0);
        const int hiL = zb - 4 + (la + 8 < 23 ? la + 8 : 23);

        const float4* sp = src + ((size_t)bc << 19);
        float4*       dp = dst + ((size_t)bc << 19);
        const float bs = bias[bc & 3];

        const int  gy0 = y0 - 4 + trow;
        const int  gy1 = y0 + 4 + trow;
        const bool lv0 = ((unsigned)gy0 < 128u);
        const bool lv1 = ((unsigned)gy1 < 128u);
        const int  off0 = (lv0 ? gy0 : 0) * 32 + col;
        const int  off1 = (lv1 ? gy1 : 0) * 32 + col;
        const int  yd0 = ((unsigned)((gy0 >> 3) - ty + 1) < 3u) ? ((gy0 >> 3) - ty + 1) : 1;
        const int  yd1 = ((unsigned)((gy1 >> 3) - ty + 1) < 3u) ? ((gy1 >> 3) - ty + 1) : 1;

        const int   r1  = (g < 3) ? g : g + 8;         // s1 rows {0,1,2,11,12,13}
        const float ym1 = ((unsigned)(y0 - 3 + r1) < 128u) ? 1.f : 0.f;
        const int   ci1 = (r1 + 1) * 32 + col;
        const int   R2  = (g < 2) ? g : g + 8;         // s2 rows {0,1,10,11}
        const float ym2 = ((unsigned)(y0 - 2 + R2) < 128u) ? 1.f : 0.f;
        const int   ci2 = (R2 + 2) * 32 + col;
        const int   S3  = g * 9;                       // s3 rows {0,9}
        const float ym3 = ((unsigned)(y0 - 1 + S3) < 128u) ? 1.f : 0.f;
        const int   ci3 = (S3 + 3) * 32 + col;

        const int go4 = (y0 + trow) * 32 + col;

        float4 pf0 = f4z, pf1 = f4z;
        float4 p1m=f4z,p1c=f4z,p1p=f4z;
        float4 p2m=f4z,p2c=f4z,p2p=f4z;
        float4 p3m=f4z,p3c=f4z,p3p=f4z;
        float4 o1m=f4z,o1c=f4z,o1p=f4z;
        float4 q1m=f4z,q1c=f4z,q1p=f4z;
        float4 q2m=f4z,q2c=f4z,q2p=f4z;
        float4 vH = f4z;
        double part = 0.0;

        auto st7 = [&](const float4& zm, const float4& cc, const float4& zp,
                       const float4& u, const float4& d, float ym) -> float4 {
            float lf = __shfl_up(cc.w, 1, 64)   * lmask;
            float rt = __shfl_down(cc.x, 1, 64) * rmask;
            float4 v;
            v.x = fmaxf((cc.x + lf   + cc.y + u.x + d.x + zm.x + zp.x) * wk + bs, 0.f) * ym;
            v.y = fmaxf((cc.y + cc.x + cc.z + u.y + d.y + zm.y + zp.y) * wk + bs, 0.f) * ym;
            v.z = fmaxf((cc.z + cc.y + cc.w + u.z + d.z + zm.z + zp.z) * wk + bs, 0.f) * ym;
            v.w = fmaxf((cc.w + cc.z + rt   + u.w + d.w + zm.w + zp.w) * wk + bs, 0.f) * ym;
            return v;
        };
        auto s1at = [&](int z, int ci, float ym) -> float4 {
            const float4* pzm = lin + SLOT4(z - 1) * E4_INP4;
            const float4* pzc = lin + SLOT4(z)     * E4_INP4;
            const float4* pzp = lin + SLOT4(z + 1) * E4_INP4;
            return st7(pzm[ci], pzc[ci], pzp[ci], pzc[ci - 32], pzc[ci + 32], ym);
        };
        auto prefetch = [&](int L) {
            pf0 = f4z; pf1 = f4z;
            if (L >= zb - 4 && L <= zb + 19 && (unsigned)L < 128u) {
                const int zi = (L >> 4) - tz + 1;
                const int sh = L & 15;
                const float4* zp = sp + ((size_t)L << 12);
                if (lv0 && ((sf[zi * 3 + yd0] >> sh) & 1)) pf0 = zp[off0];
                if (lv1 && ((sf[zi * 3 + yd1] >> sh) & 1)) pf1 = zp[off1];
            }
        };
        auto commit = [&](int L) {
            float4* sl = lin + SLOT4(L) * E4_INP4;
            sl[trow * 32 + col]       = pf0;
            sl[(trow + 8) * 32 + col] = pf1;
        };

        prefetch(loL);
        for (int L = loL; L <= hiL; ++L) {
            commit(L);
            __syncthreads();                // publishes votes for zs = L-5
            const int zs = L - 5;
            if (store && zs >= zb && voteArr[zs - zb] != 0)
                dp[((size_t)zs << 12) + go4] = vH;
            if (L < hiL) prefetch(L + 1);

            // ---- s1(z = L-1) ----
            {
                const int z = L - 1, ib = z - (zb - 4);
                float4 vp = f4z, vo = f4z, vq = f4z;
                if ((unsigned)ib < 24u && ((a1 >> ib) & 1)) {
                    vp = s1at(z, (trow + 4) * 32 + col, 1.f);
                    float4* o = ls1 + SLOT2(z) * E4_S1P4;
                    if (tid < 192) o[r1 * 32 + col] = s1at(z, ci1, ym1);
                    if (tid < 128) vo = s1at(z, ci2, ym2);
                    if (tid < 64)  vq = s1at(z, ci3, ym3);
                    o[(trow + 3) * 32 + col] = vp;
                    if (z >= zb && z <= zb + 15)
                        part += (double)(c1 * (vp.x + vp.y + vp.z + vp.w));
                }
                p1m = p1c; p1c = p1p; p1p = vp;
                o1m = o1c; o1c = o1p; o1p = vo;
                q1m = q1c; q1c = q1p; q1p = vq;
            }
            // ---- s2(z = L-2) ----
            {
                const int z = L - 2, ib = z - (zb - 4);
                float4 vp = f4z, vq = f4z;
                if ((unsigned)ib < 24u && ((a2 >> ib) & 1)) {
                    const bool l1 = ((a1 >> ib) & 1);
                    const float4* s1p_ = ls1 + SLOT2(z) * E4_S1P4;
                    float4 u = l1 ? s1p_[(trow + 2) * 32 + col] : f4z;
                    float4 d = l1 ? s1p_[(trow + 4) * 32 + col] : f4z;
                    vp = st7(p1m, p1c, p1p, u, d, 1.f);
                    float4* o = ls2 + SLOT2(z) * E4_S2P4;
                    if (tid < 128) {
                        float4 u2 = l1 ? s1p_[R2 * 32 + col]       : f4z;
                        float4 d2 = l1 ? s1p_[(R2 + 2) * 32 + col] : f4z;
                        o[R2 * 32 + col] = st7(o1m, o1c, o1p, u2, d2, ym2);
                    }
                    if (tid < 64) {
                        float4 u3 = l1 ? s1p_[(S3 + 1) * 32 + col] : f4z;
                        float4 d3 = l1 ? s1p_[(S3 + 3) * 32 + col] : f4z;
                        vq = st7(q1m, q1c, q1p, u3, d3, ym3);
                    }
                    o[(trow + 2) * 32 + col] = vp;
                    if (z >= zb && z <= zb + 15)
                        part += (double)(c2 * (vp.x + vp.y + vp.z + vp.w));
                }
                p2m = p2c; p2c = p2p; p2p = vp;
                q2m = q2c; q2c = q2p; q2p = vq;
            }
            // ---- s3(z = L-3) ----
            {
                const int z = L - 3, ib = z - (zb - 4);
                float4 vp = f4z;
                if ((unsigned)ib < 24u && ((a3 >> ib) & 1)) {
                    const bool l2 = ((a2 >> ib) & 1);
                    const float4* s2p_ = ls2 + SLOT2(z) * E4_S2P4;
                    float4 u = l2 ? s2p_[(trow + 1) * 32 + col] : f4z;
                    float4 d = l2 ? s2p_[(trow + 3) * 32 + col] : f4z;
                    vp = st7(p2m, p2c, p2p, u, d, 1.f);
                    float4* o = ls3 + SLOT2(z) * E4_S3P4;
                    if (tid < 64) {
                        float4 u3 = l2 ? s2p_[S3 * 32 + col]       : f4z;
                        float4 d3 = l2 ? s2p_[(S3 + 2) * 32 + col] : f4z;
                        o[S3 * 32 + col] = st7(q2m, q2c, q2p, u3, d3, ym3);
                    }
                    o[(trow + 1) * 32 + col] = vp;
                    if (z >= zb && z <= zb + 15)
                        part += (double)(c3 * (vp.x + vp.y + vp.z + vp.w));
                }
                p3m = p3c; p3c = p3p; p3p = vp;
            }
            // ---- s4(z = L-4) : owned output ----
            {
                const int z = L - 4, ib = z - (zb - 4);
                float4 v = f4z;
                if ((unsigned)ib < 24u && ((a4 >> ib) & 1)) {
                    const bool l3 = ((a3 >> ib) & 1);
                    const float4* s3p_ = ls3 + SLOT2(z) * E4_S3P4;
                    float4 u = l3 ? s3p_[trow * 32 + col]       : f4z;
                    float4 d = l3 ? s3p_[(trow + 2) * 32 + col] : f4z;
                    v = st7(p3m, p3c, p3p, u, d, 1.f);
                    part += (double)(c4 * (v.x + v.y + v.z + v.w));
                    bool nzv = (v.x != 0.f) || (v.y != 0.f) ||
                               (v.z != 0.f) || (v.w != 0.f);
                    if (__any(nzv) && (tid & 63) == 0)
                        atomicOr(&voteArr[z - zb], 1);
                }
                vH = v;
            }
        }

        // flush the pending deferred store (plane computed at L = hiL)
        __syncthreads();
        {
            const int hp = hiL - 4;
            if (store && hp >= zb && voteArr[hp - zb] != 0)
                dp[((size_t)hp << 12) + go4] = vH;
        }

        #pragma unroll
        for (int off = 32; off > 0; off >>= 1)
            part += __shfl_down(part, off, 64);
        if ((tid & 63) == 0) wsum[tid >> 6] = part;
        __syncthreads();
        if (tid == 0) {
            int mask = 0;
            #pragma unroll
            for (int i = 0; i < 16; ++i) mask |= (voteArr[i] ? 1 : 0) << i;
            flagOut[tile] = mask;
            double tot = (wsum[0] + wsum[1] + wsum[2] + wsum[3]) * (double)weight[bc];
            atomicAdd(&accs[tile], tot);
        }
        __syncthreads();                    // tile state quiesced before next pop
    }
}

// Reduce the NACC per-tile accumulators -> scalar mean.
__global__ __launch_bounds__(1024) void finalize_kernel(
    const double* __restrict__ accs, float* __restrict__ out)
{
    __shared__ double wsum[16];
    double v = accs[threadIdx.x];
    #pragma unroll
    for (int off = 32; off > 0; off >>= 1)
        v += __shfl_down(v, off, 64);
    int lane = threadIdx.x & 63;
    int wid  = threadIdx.x >> 6;
    if (lane == 0) wsum[wid] = v;
    __syncthreads();
    if (threadIdx.x == 0) {
        double tot = 0.0;
        #pragma unroll
        for (int i = 0; i < 16; ++i) tot += wsum[i];
        out[0] = (float)(tot / (double)NTOT);
    }
}

extern "C" void kernel_launch(void* const* d_in, const int* in_sizes, int n_in,
                              void* d_out, int out_size, void* d_ws, size_t ws_size,
                              hipStream_t stream) {
    const float* in     = (const float*)d_in[0];
    const int*   tgt    = (const int*)d_in[1];
    const float* weight = (const float*)d_in[2];
    const float* kern   = (const float*)d_in[3];
    const float* bias   = (const float*)d_in[4];
    float* out = (float*)d_out;

    char* ws = (char*)d_ws;
    float*  buf0   = (float*)ws;
    float*  buf1   = (float*)(ws + (size_t)NTOT * sizeof(float));
    double* accs   = (double*)(ws + (size_t)NTOT * 2 * sizeof(float));
    int*    flagsA = (int*)(ws + (size_t)NTOT * 2 * sizeof(float) + NACC * sizeof(double));
    int*    flagsB = flagsA + 1024;
    int*    wlA    = flagsB + 1024;     // [0]=count, [1..1024]=entries
    int*    popA   = wlA + 1056;
    int*    wlB    = popA + 32;
    int*    popB   = wlB + 1056;

    // 1) fused softmax+square+erode^2 (steps 1-2): in -> buf0, masks -> flagsA
    fused_sm_erode2_kernel<<<1024, 256, 0, stream>>>(
        in, tgt, (float4*)buf0, kern, bias, weight, 1.0f, 4.0f, accs, flagsA);

    // 2) worklist for steps 3-6 (zeroes flagsB + popA)
    wl_build_kernel<<<1, 1024, 0, stream>>>(flagsA, flagsB, wlA, popA);

    // 3) erode^4 (steps 3-6): buf0 -> buf1, masks flagsA -> flagsB
    erode4_kernel<<<256, 256, 0, stream>>>(
        (const float4*)buf0, (float4*)buf1, kern, bias, weight,
        9.0f, 16.0f, 25.0f, 36.0f, 1, accs, flagsA, flagsB, wlA, popA);

    // 4) worklist for steps 7-10 (zeroes flagsA + popB)
    wl_build_kernel<<<1, 1024, 0, stream>>>(flagsB, flagsA, wlB, popB);

    // 5) erode^4 (steps 7-10): buf1, no store
    erode4_kernel<<<256, 256, 0, stream>>>(
        (const float4*)buf1, (float4*)buf0, kern, bias, weight,
        49.0f, 64.0f, 81.0f, 100.0f, 0, accs, flagsB, flagsA, wlB, popB);

    // 6) reduce + mean
    finalize_kernel<<<1, 1024, 0, stream>>>(accs, out);
}